// Round 3
// baseline (495.863 us; speedup 1.0000x reference)
//
#include <hip/hip_runtime.h>
#include <cstdint>
#include <cmath>

// Problem constants
constexpr int TT   = 256;   // tokens
constexpr int HD   = 1024;  // hidden
constexpr int IDIM = 512;   // intermediate
constexpr int NE   = 32;    // experts
constexpr int NGRP = 8;
constexpr int TKG  = 4;
constexpr int TOPK = 8;
constexpr float RSCALE = 2.5f;

// Tiling
constexpr int TM = 96;     // token tile per block
constexpr int MT = 6;      // 16-row MFMA tiles per token tile
constexpr int BSTR = 40;   // LDS transposed-weight row stride (halves): 80B, 16B-aligned, 2-way banks

typedef float     f32x4 __attribute__((ext_vector_type(4)));
typedef _Float16  half8 __attribute__((ext_vector_type(8)));

// Workspace layout (bytes)
constexpr size_t WS_CNT = 0;                           // NE ints (zeroed; 256B region)
constexpr size_t WS_TOK = 256;                         // NE*TT ints
constexpr size_t WS_WL  = WS_TOK + (size_t)NE*TT*4;    // NE*TT floats
constexpr size_t WS_A   = WS_WL  + (size_t)NE*TT*4;    // NE*TT*IDIM f16

// ---------------- Routing ----------------
__global__ __launch_bounds__(64) void k_route(
    const float* __restrict__ x, const float* __restrict__ gw,
    const float* __restrict__ bias, int* __restrict__ cnt,
    int* __restrict__ tok, float* __restrict__ wl)
{
    int t = blockIdx.x;
    int l = threadIdx.x;          // 0..63
    int e = l & 31, half = l >> 5;
    const float* xr = x + (size_t)t * HD;
    float acc = 0.f;
    int h0 = half * (HD / 2);
    for (int h = h0; h < h0 + HD / 2; ++h)
        acc += xr[h] * gw[(size_t)h * NE + e];
    acc += __shfl_down(acc, 32);
    __shared__ float sc[NE], sfc[NE];
    if (l < 32) {
        float s = 1.f / (1.f + expf(-acc));
        sc[e] = s;
        sfc[e] = s + bias[e];
    }
    __syncthreads();
    if (l == 0) {
        // group scores = sum of top-2 per group of 4
        float gs[NGRP];
        for (int g = 0; g < NGRP; ++g) {
            float m1 = -3.0e38f, m2 = -3.0e38f;
            for (int j = 0; j < 4; ++j) {
                float v = sfc[4 * g + j];
                if (v > m1) { m2 = m1; m1 = v; } else if (v > m2) m2 = v;
            }
            gs[g] = m1 + m2;
        }
        bool gsel[NGRP];
        for (int g = 0; g < NGRP; ++g) gsel[g] = false;
        for (int r = 0; r < TKG; ++r) {
            int bi = -1; float bv = -3.0e38f;
            for (int g = 0; g < NGRP; ++g)
                if (!gsel[g] && gs[g] > bv) { bv = gs[g]; bi = g; }
            gsel[bi] = true;
        }
        float masked[NE];
        for (int i = 0; i < NE; ++i) masked[i] = gsel[i >> 2] ? sfc[i] : 0.0f;
        int   idx[TOPK]; float wv[TOPK]; float wsum = 0.f;
        for (int r = 0; r < TOPK; ++r) {
            int bi = -1; float bv = -3.0e38f;
            for (int i = 0; i < NE; ++i)
                if (masked[i] > bv) { bv = masked[i]; bi = i; }
            masked[bi] = -3.0e38f;
            idx[r] = bi; wv[r] = sc[bi]; wsum += wv[r];
        }
        float inv = RSCALE / (wsum + 1e-20f);
        for (int r = 0; r < TOPK; ++r) {
            int ee = idx[r];
            int pos = atomicAdd(&cnt[ee], 1);
            tok[(size_t)ee * TT + pos] = t;
            wl [(size_t)ee * TT + pos] = wv[r] * inv;
        }
    }
}

// ---------------- Gate/Up: A = silu(X Wg) * (X Wu), per expert ----------------
__global__ __launch_bounds__(256) void k_gateup(
    const float* __restrict__ x, const float* __restrict__ Wg,
    const float* __restrict__ Wu, const int* __restrict__ cnt,
    const int* __restrict__ tok, _Float16* __restrict__ A)
{
    int e = blockIdx.x / 3, ttile = blockIdx.x % 3;
    int n_e = cnt[e];
    int row0 = ttile * TM;
    if (row0 >= n_e) return;
    int mcount = min(TM, n_e - row0);
    int mtc = (mcount + 15) >> 4;
    int i0 = blockIdx.y * 64;
    int tid = threadIdx.x;
    int lane = tid & 63, w = tid >> 6;

    __shared__ __align__(16) _Float16 Bg[64 * BSTR];
    __shared__ __align__(16) _Float16 Bu[64 * BSTR];

    // per-lane A-row base pointers (gathered token rows, clamped)
    const float* abase[MT];
#pragma unroll
    for (int mt = 0; mt < MT; ++mt) {
        int slot = row0 + mt * 16 + (lane & 15);
        slot = slot < n_e ? slot : n_e - 1;
        int tk = tok[(size_t)e * TT + slot];
        abase[mt] = x + (size_t)tk * HD;
    }

    // staging mapping: each thread owns one column (sn) and one k-group (skg)
    int sn = lane;            // 0..63
    int skg = w;              // 0..3 -> k rows skg*8 .. skg*8+7
    const float* gptr = Wg + ((size_t)e * HD + skg * 8) * IDIM + i0 + sn;
    const float* uptr = Wu + ((size_t)e * HD + skg * 8) * IDIM + i0 + sn;

    f32x4 accG[MT], accU[MT];
#pragma unroll
    for (int mt = 0; mt < MT; ++mt) {
        accG[mt] = (f32x4){0.f, 0.f, 0.f, 0.f};
        accU[mt] = (f32x4){0.f, 0.f, 0.f, 0.f};
    }

    float rg[8], ru[8];
#pragma unroll
    for (int j = 0; j < 8; ++j) { rg[j] = gptr[(size_t)j * IDIM]; ru[j] = uptr[(size_t)j * IDIM]; }

    constexpr int NK = HD / 32;
    for (int ks = 0; ks < NK; ++ks) {
        __syncthreads();
        half8 hg, hu;
#pragma unroll
        for (int j = 0; j < 8; ++j) { hg[j] = (_Float16)rg[j]; hu[j] = (_Float16)ru[j]; }
        *(half8*)&Bg[sn * BSTR + skg * 8] = hg;
        *(half8*)&Bu[sn * BSTR + skg * 8] = hu;
        __syncthreads();
        if (ks + 1 < NK) {
            const float* g2 = gptr + (size_t)(ks + 1) * 32 * IDIM;
            const float* u2 = uptr + (size_t)(ks + 1) * 32 * IDIM;
#pragma unroll
            for (int j = 0; j < 8; ++j) { rg[j] = g2[(size_t)j * IDIM]; ru[j] = u2[(size_t)j * IDIM]; }
        }
        int koff = (lane >> 4) * 8;
        half8 bg = *(const half8*)&Bg[(w * 16 + (lane & 15)) * BSTR + koff];
        half8 bu = *(const half8*)&Bu[(w * 16 + (lane & 15)) * BSTR + koff];
#pragma unroll
        for (int mt = 0; mt < MT; ++mt) {
            if (mt < mtc) {
                const float* ap = abase[mt] + ks * 32 + koff;
                f32x4 a0 = *(const f32x4*)ap;
                f32x4 a1 = *(const f32x4*)(ap + 4);
                half8 af;
                af[0] = (_Float16)a0.x; af[1] = (_Float16)a0.y;
                af[2] = (_Float16)a0.z; af[3] = (_Float16)a0.w;
                af[4] = (_Float16)a1.x; af[5] = (_Float16)a1.y;
                af[6] = (_Float16)a1.z; af[7] = (_Float16)a1.w;
                accG[mt] = __builtin_amdgcn_mfma_f32_16x16x32_f16(af, bg, accG[mt], 0, 0, 0);
                accU[mt] = __builtin_amdgcn_mfma_f32_16x16x32_f16(af, bu, accU[mt], 0, 0, 0);
            }
        }
    }

    int col = i0 + w * 16 + (lane & 15);
#pragma unroll
    for (int mt = 0; mt < MT; ++mt) {
        if (mt < mtc) {
#pragma unroll
            for (int r = 0; r < 4; ++r) {
                int m = ((lane >> 4) << 2) + r;
                int row = row0 + mt * 16 + m;
                float g = accG[mt][r], u = accU[mt][r];
                float a = (g / (1.f + expf(-g))) * u;
                A[((size_t)e * TT + row) * IDIM + col] = (_Float16)a;
            }
        }
    }
}

// ---------------- Down: out += w * (A Wd), per expert ----------------
__global__ __launch_bounds__(256) void k_down(
    const _Float16* __restrict__ A, const float* __restrict__ Wd,
    const int* __restrict__ cnt, const int* __restrict__ tok,
    const float* __restrict__ wl, float* __restrict__ outf)
{
    int e = blockIdx.x / 3, ttile = blockIdx.x % 3;
    int n_e = cnt[e];
    int row0 = ttile * TM;
    if (row0 >= n_e) return;
    int mcount = min(TM, n_e - row0);
    int mtc = (mcount + 15) >> 4;
    int h0 = blockIdx.y * 64;
    int tid = threadIdx.x;
    int lane = tid & 63, w = tid >> 6;

    __shared__ __align__(16) _Float16 Bd[64 * BSTR];

    const _Float16* abase[MT];
#pragma unroll
    for (int mt = 0; mt < MT; ++mt)
        abase[mt] = A + ((size_t)e * TT + row0 + mt * 16 + (lane & 15)) * IDIM;

    int sn = lane;
    int skg = w;
    const float* dptr = Wd + ((size_t)e * IDIM + skg * 8) * HD + h0 + sn;

    f32x4 acc[MT];
#pragma unroll
    for (int mt = 0; mt < MT; ++mt) acc[mt] = (f32x4){0.f, 0.f, 0.f, 0.f};

    float rd[8];
#pragma unroll
    for (int j = 0; j < 8; ++j) rd[j] = dptr[(size_t)j * HD];

    constexpr int NK = IDIM / 32;
    for (int ks = 0; ks < NK; ++ks) {
        __syncthreads();
        half8 hd;
#pragma unroll
        for (int j = 0; j < 8; ++j) hd[j] = (_Float16)rd[j];
        *(half8*)&Bd[sn * BSTR + skg * 8] = hd;
        __syncthreads();
        if (ks + 1 < NK) {
            const float* d2 = dptr + (size_t)(ks + 1) * 32 * HD;
#pragma unroll
            for (int j = 0; j < 8; ++j) rd[j] = d2[(size_t)j * HD];
        }
        int koff = (lane >> 4) * 8;
        half8 bd = *(const half8*)&Bd[(w * 16 + (lane & 15)) * BSTR + koff];
#pragma unroll
        for (int mt = 0; mt < MT; ++mt) {
            if (mt < mtc) {
                half8 af = *(const half8*)(abase[mt] + ks * 32 + koff);
                acc[mt] = __builtin_amdgcn_mfma_f32_16x16x32_f16(af, bd, acc[mt], 0, 0, 0);
            }
        }
    }

    int col = h0 + w * 16 + (lane & 15);
#pragma unroll
    for (int mt = 0; mt < MT; ++mt) {
        if (mt < mtc) {
#pragma unroll
            for (int r = 0; r < 4; ++r) {
                int m = ((lane >> 4) << 2) + r;
                int slot = row0 + mt * 16 + m;
                if (slot < n_e) {
                    int t  = tok[(size_t)e * TT + slot];
                    float wt = wl[(size_t)e * TT + slot];
                    atomicAdd(&outf[(size_t)t * HD + col], wt * acc[mt][r]);
                }
            }
        }
    }
}

extern "C" void kernel_launch(void* const* d_in, const int* in_sizes, int n_in,
                              void* d_out, int out_size, void* d_ws, size_t ws_size,
                              hipStream_t stream) {
    const float* x    = (const float*)d_in[0];
    const float* gw   = (const float*)d_in[1];
    const float* bias = (const float*)d_in[2];
    const float* Wg   = (const float*)d_in[3];
    const float* Wu   = (const float*)d_in[4];
    const float* Wd   = (const float*)d_in[5];
    float* out = (float*)d_out;   // reference output dtype is float32

    char* ws = (char*)d_ws;
    int*      cnt = (int*)(ws + WS_CNT);
    int*      tok = (int*)(ws + WS_TOK);
    float*    wl  = (float*)(ws + WS_WL);
    _Float16* A   = (_Float16*)(ws + WS_A);

    hipMemsetAsync(ws, 0, 256, stream);                       // expert counters
    hipMemsetAsync(out, 0, (size_t)TT * HD * 4, stream);      // f32 output accumulator

    k_route<<<TT, 64, 0, stream>>>(x, gw, bias, cnt, tok, wl);
    k_gateup<<<dim3(NE * 3, IDIM / 64), 256, 0, stream>>>(x, Wg, Wu, cnt, tok, A);
    k_down<<<dim3(NE * 3, HD / 64), 256, 0, stream>>>(A, Wd, cnt, tok, wl, out);
}

// Round 4
// 327.968 us; speedup vs baseline: 1.5119x; 1.5119x over previous
//
#include <hip/hip_runtime.h>
#include <cstdint>
#include <cmath>

// Problem constants
constexpr int TT   = 256;   // tokens
constexpr int HD   = 1024;  // hidden
constexpr int IDIM = 512;   // intermediate
constexpr int NE   = 32;    // experts
constexpr int NGRP = 8;
constexpr int TKG  = 4;
constexpr int TOPK = 8;
constexpr float RSCALE = 2.5f;

// Tiling
constexpr int TM = 96;     // token tile per block
constexpr int MT = 6;      // 16-row MFMA tiles per token tile
constexpr int BSTR = 40;   // LDS transposed-weight row stride (halves): 80B, 16B-aligned, 2-way banks

typedef float     f32x4 __attribute__((ext_vector_type(4)));
typedef _Float16  half8 __attribute__((ext_vector_type(8)));

// Workspace layout (bytes)
constexpr size_t WS_CNT = 0;                           // NE ints (zeroed; 256B region)
constexpr size_t WS_TOK = 256;                         // NE*TT ints
constexpr size_t WS_WL  = WS_TOK + (size_t)NE*TT*4;    // NE*TT floats
constexpr size_t WS_A   = WS_WL  + (size_t)NE*TT*4;    // NE*TT*IDIM f16

// ---------------- Routing ----------------
// 256 threads/token: thread (c = tid>>4, e2 = (tid&15)*2) computes a 64-long
// partial dot for an expert PAIR (float2 loads, coalesced 128B/row).
// LDS reduce 16 partials -> logits; serial group-top-k on thread 0.
__global__ __launch_bounds__(256) void k_route(
    const float* __restrict__ x, const float* __restrict__ gw,
    const float* __restrict__ bias, int* __restrict__ cnt,
    int* __restrict__ tok, float* __restrict__ wl)
{
    int t = blockIdx.x;
    int tid = threadIdx.x;
    int e2 = (tid & 15) * 2;
    int c  = tid >> 4;            // 0..15
    const float* xr = x + (size_t)t * HD;

    float a0 = 0.f, a1 = 0.f;
    int h0 = c * (HD / 16);       // 64 h-values per chunk
#pragma unroll 8
    for (int h = h0; h < h0 + HD / 16; ++h) {
        float xv = xr[h];
        float2 wv = *(const float2*)&gw[(size_t)h * NE + e2];
        a0 += xv * wv.x;
        a1 += xv * wv.y;
    }

    __shared__ float part[16][NE];
    part[c][e2]     = a0;
    part[c][e2 + 1] = a1;
    __syncthreads();

    __shared__ float sc[NE], sfc[NE];
    if (tid < NE) {
        float s = 0.f;
#pragma unroll
        for (int cc = 0; cc < 16; ++cc) s += part[cc][tid];
        float sig = 1.f / (1.f + expf(-s));
        sc[tid]  = sig;
        sfc[tid] = sig + bias[tid];
    }
    __syncthreads();

    if (tid == 0) {
        // group scores = sum of top-2 per group of 4
        float gs[NGRP];
        for (int g = 0; g < NGRP; ++g) {
            float m1 = -3.0e38f, m2 = -3.0e38f;
            for (int j = 0; j < 4; ++j) {
                float v = sfc[4 * g + j];
                if (v > m1) { m2 = m1; m1 = v; } else if (v > m2) m2 = v;
            }
            gs[g] = m1 + m2;
        }
        bool gsel[NGRP];
        for (int g = 0; g < NGRP; ++g) gsel[g] = false;
        for (int r = 0; r < TKG; ++r) {
            int bi = -1; float bv = -3.0e38f;
            for (int g = 0; g < NGRP; ++g)
                if (!gsel[g] && gs[g] > bv) { bv = gs[g]; bi = g; }
            gsel[bi] = true;
        }
        float masked[NE];
        for (int i = 0; i < NE; ++i) masked[i] = gsel[i >> 2] ? sfc[i] : 0.0f;
        int   idx[TOPK]; float wv[TOPK]; float wsum = 0.f;
        for (int r = 0; r < TOPK; ++r) {
            int bi = -1; float bv = -3.0e38f;
            for (int i = 0; i < NE; ++i)
                if (masked[i] > bv) { bv = masked[i]; bi = i; }
            masked[bi] = -3.0e38f;
            idx[r] = bi; wv[r] = sc[bi]; wsum += wv[r];
        }
        float inv = RSCALE / (wsum + 1e-20f);
        for (int r = 0; r < TOPK; ++r) {
            int ee = idx[r];
            int pos = atomicAdd(&cnt[ee], 1);
            tok[(size_t)ee * TT + pos] = t;
            wl [(size_t)ee * TT + pos] = wv[r] * inv;
        }
    }
}

// ---------------- Gate/Up: A = silu(X Wg) * (X Wu), per expert ----------------
__global__ __launch_bounds__(256) void k_gateup(
    const float* __restrict__ x, const float* __restrict__ Wg,
    const float* __restrict__ Wu, const int* __restrict__ cnt,
    const int* __restrict__ tok, _Float16* __restrict__ A)
{
    int e = blockIdx.x / 3, ttile = blockIdx.x % 3;
    int n_e = cnt[e];
    int row0 = ttile * TM;
    if (row0 >= n_e) return;
    int mcount = min(TM, n_e - row0);
    int mtc = (mcount + 15) >> 4;
    int i0 = blockIdx.y * 64;
    int tid = threadIdx.x;
    int lane = tid & 63, w = tid >> 6;

    __shared__ __align__(16) _Float16 Bg[64 * BSTR];
    __shared__ __align__(16) _Float16 Bu[64 * BSTR];

    // per-lane A-row base pointers (gathered token rows, clamped)
    const float* abase[MT];
#pragma unroll
    for (int mt = 0; mt < MT; ++mt) {
        int slot = row0 + mt * 16 + (lane & 15);
        slot = slot < n_e ? slot : n_e - 1;
        int tk = tok[(size_t)e * TT + slot];
        abase[mt] = x + (size_t)tk * HD;
    }

    // staging mapping: each thread owns one column (sn) and one k-group (skg)
    int sn = lane;            // 0..63
    int skg = w;              // 0..3 -> k rows skg*8 .. skg*8+7
    const float* gptr = Wg + ((size_t)e * HD + skg * 8) * IDIM + i0 + sn;
    const float* uptr = Wu + ((size_t)e * HD + skg * 8) * IDIM + i0 + sn;

    f32x4 accG[MT], accU[MT];
#pragma unroll
    for (int mt = 0; mt < MT; ++mt) {
        accG[mt] = (f32x4){0.f, 0.f, 0.f, 0.f};
        accU[mt] = (f32x4){0.f, 0.f, 0.f, 0.f};
    }

    float rg[8], ru[8];
#pragma unroll
    for (int j = 0; j < 8; ++j) { rg[j] = gptr[(size_t)j * IDIM]; ru[j] = uptr[(size_t)j * IDIM]; }

    constexpr int NK = HD / 32;
    for (int ks = 0; ks < NK; ++ks) {
        __syncthreads();
        half8 hg, hu;
#pragma unroll
        for (int j = 0; j < 8; ++j) { hg[j] = (_Float16)rg[j]; hu[j] = (_Float16)ru[j]; }
        *(half8*)&Bg[sn * BSTR + skg * 8] = hg;
        *(half8*)&Bu[sn * BSTR + skg * 8] = hu;
        __syncthreads();
        if (ks + 1 < NK) {
            const float* g2 = gptr + (size_t)(ks + 1) * 32 * IDIM;
            const float* u2 = uptr + (size_t)(ks + 1) * 32 * IDIM;
#pragma unroll
            for (int j = 0; j < 8; ++j) { rg[j] = g2[(size_t)j * IDIM]; ru[j] = u2[(size_t)j * IDIM]; }
        }
        int koff = (lane >> 4) * 8;
        half8 bg = *(const half8*)&Bg[(w * 16 + (lane & 15)) * BSTR + koff];
        half8 bu = *(const half8*)&Bu[(w * 16 + (lane & 15)) * BSTR + koff];
#pragma unroll
        for (int mt = 0; mt < MT; ++mt) {
            if (mt < mtc) {
                const float* ap = abase[mt] + ks * 32 + koff;
                f32x4 a0 = *(const f32x4*)ap;
                f32x4 a1 = *(const f32x4*)(ap + 4);
                half8 af;
                af[0] = (_Float16)a0.x; af[1] = (_Float16)a0.y;
                af[2] = (_Float16)a0.z; af[3] = (_Float16)a0.w;
                af[4] = (_Float16)a1.x; af[5] = (_Float16)a1.y;
                af[6] = (_Float16)a1.z; af[7] = (_Float16)a1.w;
                accG[mt] = __builtin_amdgcn_mfma_f32_16x16x32_f16(af, bg, accG[mt], 0, 0, 0);
                accU[mt] = __builtin_amdgcn_mfma_f32_16x16x32_f16(af, bu, accU[mt], 0, 0, 0);
            }
        }
    }

    int col = i0 + w * 16 + (lane & 15);
#pragma unroll
    for (int mt = 0; mt < MT; ++mt) {
        if (mt < mtc) {
#pragma unroll
            for (int r = 0; r < 4; ++r) {
                int m = ((lane >> 4) << 2) + r;
                int row = row0 + mt * 16 + m;
                float g = accG[mt][r], u = accU[mt][r];
                float a = (g / (1.f + expf(-g))) * u;
                A[((size_t)e * TT + row) * IDIM + col] = (_Float16)a;
            }
        }
    }
}

// ---------------- Down: out += w * (A Wd), per expert ----------------
__global__ __launch_bounds__(256) void k_down(
    const _Float16* __restrict__ A, const float* __restrict__ Wd,
    const int* __restrict__ cnt, const int* __restrict__ tok,
    const float* __restrict__ wl, float* __restrict__ outf)
{
    int e = blockIdx.x / 3, ttile = blockIdx.x % 3;
    int n_e = cnt[e];
    int row0 = ttile * TM;
    if (row0 >= n_e) return;
    int mcount = min(TM, n_e - row0);
    int mtc = (mcount + 15) >> 4;
    int h0 = blockIdx.y * 64;
    int tid = threadIdx.x;
    int lane = tid & 63, w = tid >> 6;

    __shared__ __align__(16) _Float16 Bd[64 * BSTR];

    const _Float16* abase[MT];
#pragma unroll
    for (int mt = 0; mt < MT; ++mt)
        abase[mt] = A + ((size_t)e * TT + row0 + mt * 16 + (lane & 15)) * IDIM;

    int sn = lane;
    int skg = w;
    const float* dptr = Wd + ((size_t)e * IDIM + skg * 8) * HD + h0 + sn;

    f32x4 acc[MT];
#pragma unroll
    for (int mt = 0; mt < MT; ++mt) acc[mt] = (f32x4){0.f, 0.f, 0.f, 0.f};

    float rd[8];
#pragma unroll
    for (int j = 0; j < 8; ++j) rd[j] = dptr[(size_t)j * HD];

    constexpr int NK = IDIM / 32;
    for (int ks = 0; ks < NK; ++ks) {
        __syncthreads();
        half8 hd;
#pragma unroll
        for (int j = 0; j < 8; ++j) hd[j] = (_Float16)rd[j];
        *(half8*)&Bd[sn * BSTR + skg * 8] = hd;
        __syncthreads();
        if (ks + 1 < NK) {
            const float* d2 = dptr + (size_t)(ks + 1) * 32 * HD;
#pragma unroll
            for (int j = 0; j < 8; ++j) rd[j] = d2[(size_t)j * HD];
        }
        int koff = (lane >> 4) * 8;
        half8 bd = *(const half8*)&Bd[(w * 16 + (lane & 15)) * BSTR + koff];
#pragma unroll
        for (int mt = 0; mt < MT; ++mt) {
            if (mt < mtc) {
                half8 af = *(const half8*)(abase[mt] + ks * 32 + koff);
                acc[mt] = __builtin_amdgcn_mfma_f32_16x16x32_f16(af, bd, acc[mt], 0, 0, 0);
            }
        }
    }

    int col = h0 + w * 16 + (lane & 15);
#pragma unroll
    for (int mt = 0; mt < MT; ++mt) {
        if (mt < mtc) {
#pragma unroll
            for (int r = 0; r < 4; ++r) {
                int m = ((lane >> 4) << 2) + r;
                int slot = row0 + mt * 16 + m;
                if (slot < n_e) {
                    int t  = tok[(size_t)e * TT + slot];
                    float wt = wl[(size_t)e * TT + slot];
                    atomicAdd(&outf[(size_t)t * HD + col], wt * acc[mt][r]);
                }
            }
        }
    }
}

extern "C" void kernel_launch(void* const* d_in, const int* in_sizes, int n_in,
                              void* d_out, int out_size, void* d_ws, size_t ws_size,
                              hipStream_t stream) {
    const float* x    = (const float*)d_in[0];
    const float* gw   = (const float*)d_in[1];
    const float* bias = (const float*)d_in[2];
    const float* Wg   = (const float*)d_in[3];
    const float* Wu   = (const float*)d_in[4];
    const float* Wd   = (const float*)d_in[5];
    float* out = (float*)d_out;   // reference output dtype is float32

    char* ws = (char*)d_ws;
    int*      cnt = (int*)(ws + WS_CNT);
    int*      tok = (int*)(ws + WS_TOK);
    float*    wl  = (float*)(ws + WS_WL);
    _Float16* A   = (_Float16*)(ws + WS_A);

    hipMemsetAsync(ws, 0, 256, stream);                       // expert counters
    hipMemsetAsync(out, 0, (size_t)TT * HD * 4, stream);      // f32 output accumulator

    k_route<<<TT, 256, 0, stream>>>(x, gw, bias, cnt, tok, wl);
    k_gateup<<<dim3(NE * 3, IDIM / 64), 256, 0, stream>>>(x, Wg, Wu, cnt, tok, A);
    k_down<<<dim3(NE * 3, HD / 64), 256, 0, stream>>>(A, Wd, cnt, tok, wl, out);
}